// Round 7
// baseline (438.222 us; speedup 1.0000x reference)
//
#include <hip/hip_runtime.h>
#include <hip/hip_fp16.h>
#include <math.h>

#define NN 100000
#define NE 3200000
#define CF 512

#define NPARTS  8
#define PART    12500              // nodes per partition (50 KB LDS hist)
#define NSLICES 64                 // edge slices
#define EPB     (NE / NSLICES)     // 50000 edges per block (divisible by 16)
#define NPB     (NSLICES * NPARTS) // 512 blocks -> 2 blocks/CU

// ---- ws layout (bytes), total 13,600,004 ----
// part : u16/half [NPB][PART] @ 0           (12,800,000) -- reused: deg(u16) then s(half)
// g    : float[NN]            @ 12,800,000  (400,000)
// dinv : float[NN]            @ 13,200,000  (400,000)
// flag : int                  @ 13,600,000
#define OFF_G    12800000
#define OFF_DINV 13200000
#define OFF_FLAG 13600000

// Detect int64 edge_index layout (values < 2^31 => high words all zero)
__global__ void detect_i64_kernel(const unsigned int* e32, int* flag) {
    unsigned v = e32[2 * threadIdx.x + 1];
    unsigned long long m = __ballot(v != 0u);
    if (threadIdx.x == 0) *flag = (m == 0ULL) ? 1 : 0;
}

// 4 consecutive cols / rows starting at edge e (e % 4 == 0)
__device__ __forceinline__ int4 load_col4(const int* __restrict__ e32, bool f64, int e) {
    if (f64) {
        const int4* q = (const int4*)(e32 + 2 * (NE + e));
        int4 a = q[0], b = q[1];
        return make_int4(a.x, a.z, b.x, b.z);
    }
    return *(const int4*)(e32 + NE + e);
}
__device__ __forceinline__ int4 load_row4(const int* __restrict__ e32, bool f64, int e) {
    if (f64) {
        const int4* q = (const int4*)(e32 + 2 * e);
        int4 a = q[0], b = q[1];
        return make_int4(a.x, a.z, b.x, b.z);
    }
    return *(const int4*)(e32 + e);
}

// In-degree histogram: 16 cols/thread/iter (4 int4 in flight), LDS-privatized.
// Swizzle: p = blk>>6, s = blk&63 -> 8 partition-siblings of a slice share an XCD L2.
__global__ __launch_bounds__(1024) void deg_lds_kernel(const int* __restrict__ e32,
                                                       const int* __restrict__ flag,
                                                       unsigned short* __restrict__ deg_part) {
    __shared__ int h[PART];
    int tid = threadIdx.x;
    for (int i = tid; i < PART; i += 1024) h[i] = 0;
    __syncthreads();
    int p = blockIdx.x >> 6;
    int s = blockIdx.x & 63;
    int lo = p * PART;
    bool f64 = (*flag) != 0;
    int base = s * EPB, end = base + EPB;
    for (int e = base + tid * 16; e + 16 <= end; e += 1024 * 16) {
        int4 c0 = load_col4(e32, f64, e + 0);
        int4 c1 = load_col4(e32, f64, e + 4);
        int4 c2 = load_col4(e32, f64, e + 8);
        int4 c3 = load_col4(e32, f64, e + 12);
        #define DEG1(v) { unsigned l = (unsigned)((v) - lo); if (l < PART) atomicAdd(&h[l], 1); }
        DEG1(c0.x) DEG1(c0.y) DEG1(c0.z) DEG1(c0.w)
        DEG1(c1.x) DEG1(c1.y) DEG1(c1.z) DEG1(c1.w)
        DEG1(c2.x) DEG1(c2.y) DEG1(c2.z) DEG1(c2.w)
        DEG1(c3.x) DEG1(c3.y) DEG1(c3.z) DEG1(c3.w)
        #undef DEG1
    }
    __syncthreads();
    unsigned short* out = deg_part + (size_t)blockIdx.x * PART;
    for (int i = tid; i < PART; i += 1024) out[i] = (unsigned short)h[i];
}

// dinv[i] = rsqrt(1 + sum_slices deg_part[.][i])
__global__ void dinv_kernel(const unsigned short* __restrict__ deg_part,
                            float* __restrict__ dinv) {
    int i = blockIdx.x * blockDim.x + threadIdx.x;
    if (i >= NN) return;
    int p = i / PART, l = i - p * PART;
    const unsigned short* bp = deg_part + ((size_t)(p << 6)) * PART + l;
    int d = 1;
#pragma unroll
    for (int s = 0; s < NSLICES; ++s) d += bp[(size_t)s * PART];
    dinv[i] = rsqrtf((float)d);
}

// One wave per node: g[i] = dot(x[i,:], W) * dinv[i]
__global__ __launch_bounds__(256) void node_kernel(const float* __restrict__ x,
                                                   const float* __restrict__ W,
                                                   const float* __restrict__ dinv,
                                                   float* __restrict__ g) {
    int wave = (int)((blockIdx.x * blockDim.x + threadIdx.x) >> 6);
    int lane = threadIdx.x & 63;
    if (wave >= NN) return;
    const float4* xr = (const float4*)(x + (size_t)wave * CF);
    const float4* Wr = (const float4*)W;
    float sum = 0.f;
#pragma unroll
    for (int j = 0; j < 2; ++j) {
        float4 a = xr[lane + 64 * j];
        float4 w = Wr[lane + 64 * j];
        sum += a.x * w.x + a.y * w.y + a.z * w.z + a.w * w.w;
    }
#pragma unroll
    for (int off = 32; off >= 1; off >>= 1)
        sum += __shfl_down(sum, off, 64);
    if (lane == 0) g[wave] = sum * dinv[wave];
}

// Edge scatter: 16 edges/thread/iter, dense coalesced col+row int4 loads,
// predicated g gathers (independent, high MLP), LDS hist, half partials out.
__global__ __launch_bounds__(1024) void scatter_lds_kernel(const int* __restrict__ e32,
                                                           const int* __restrict__ flag,
                                                           const float* __restrict__ g,
                                                           __half* __restrict__ s_part) {
    __shared__ float h[PART];
    int tid = threadIdx.x;
    for (int i = tid; i < PART; i += 1024) h[i] = 0.f;
    __syncthreads();
    int p = blockIdx.x >> 6;
    int s = blockIdx.x & 63;
    int lo = p * PART;
    bool f64 = (*flag) != 0;
    int base = s * EPB, end = base + EPB;
    for (int e = base + tid * 16; e + 16 <= end; e += 1024 * 16) {
        int4 c0 = load_col4(e32, f64, e + 0);
        int4 c1 = load_col4(e32, f64, e + 4);
        int4 c2 = load_col4(e32, f64, e + 8);
        int4 c3 = load_col4(e32, f64, e + 12);
        int4 r0 = load_row4(e32, f64, e + 0);
        int4 r1 = load_row4(e32, f64, e + 4);
        int4 r2 = load_row4(e32, f64, e + 8);
        int4 r3 = load_row4(e32, f64, e + 12);
        #define SC1(cv, rv) { unsigned l = (unsigned)((cv) - lo); \
                              if (l < PART) atomicAdd(&h[l], g[rv]); }
        SC1(c0.x, r0.x) SC1(c0.y, r0.y) SC1(c0.z, r0.z) SC1(c0.w, r0.w)
        SC1(c1.x, r1.x) SC1(c1.y, r1.y) SC1(c1.z, r1.z) SC1(c1.w, r1.w)
        SC1(c2.x, r2.x) SC1(c2.y, r2.y) SC1(c2.z, r2.z) SC1(c2.w, r2.w)
        SC1(c3.x, r3.x) SC1(c3.y, r3.y) SC1(c3.z, r3.z) SC1(c3.w, r3.w)
        #undef SC1
    }
    __syncthreads();
    __half* out = s_part + (size_t)blockIdx.x * PART;
    for (int i = tid; i < PART; i += 1024) out[i] = __float2half(h[i]);
}

// out[i] = sigmoid(dinv[i] * (sum_slices s_part[.][i] + g[i]) + b)
__global__ void final_kernel(const __half* __restrict__ s_part,
                             const float* __restrict__ g,
                             const float* __restrict__ dinv,
                             const float* __restrict__ b,
                             float* __restrict__ out) {
    int i = blockIdx.x * blockDim.x + threadIdx.x;
    if (i >= NN) return;
    int p = i / PART, l = i - p * PART;
    const __half* bp = s_part + ((size_t)(p << 6)) * PART + l;
    float acc = g[i];
#pragma unroll
    for (int s = 0; s < NSLICES; ++s) acc += __half2float(bp[(size_t)s * PART]);
    float v = dinv[i] * acc + b[0];
    out[i] = 1.f / (1.f + expf(-v));
}

extern "C" void kernel_launch(void* const* d_in, const int* in_sizes, int n_in,
                              void* d_out, int out_size, void* d_ws, size_t ws_size,
                              hipStream_t stream) {
    const float* x = (const float*)d_in[0];
    const int* eidx = (const int*)d_in[1];
    const float* W = (const float*)d_in[2];
    const float* b = (const float*)d_in[3];
    float* out = (float*)d_out;

    char* ws = (char*)d_ws;
    unsigned short* part_u16 = (unsigned short*)(ws);  // deg partials (reused as half)
    __half* part_h = (__half*)(ws);
    float* g = (float*)(ws + OFF_G);
    float* dinv = (float*)(ws + OFF_DINV);
    int* flag = (int*)(ws + OFF_FLAG);

    detect_i64_kernel<<<1, 64, 0, stream>>>((const unsigned int*)eidx, flag);
    deg_lds_kernel<<<NPB, 1024, 0, stream>>>(eidx, flag, part_u16);
    dinv_kernel<<<(NN + 255) / 256, 256, 0, stream>>>(part_u16, dinv);
    node_kernel<<<(NN * 64 + 255) / 256, 256, 0, stream>>>(x, W, dinv, g);
    scatter_lds_kernel<<<NPB, 1024, 0, stream>>>(eidx, flag, g, part_h);
    final_kernel<<<(NN + 255) / 256, 256, 0, stream>>>(part_h, g, dinv, b, out);
}